// Round 1
// baseline (577.175 us; speedup 1.0000x reference)
//
#include <hip/hip_runtime.h>
#include <hip/hip_bf16.h>

typedef unsigned short u16;
typedef __attribute__((ext_vector_type(8))) short short8v;
typedef __attribute__((ext_vector_type(4))) float f32x4;

__device__ __forceinline__ u16 f2bf(float f) {
    union { float f; unsigned int u; } x; x.f = f;
    unsigned int u = x.u;
    unsigned int r = (u + 0x7FFFu + ((u >> 16) & 1u)) >> 16;
    return (u16)r;
}
__device__ __forceinline__ float bf2f(u16 h) {
    union { unsigned int u; float f; } x; x.u = ((unsigned int)h) << 16;
    return x.f;
}

// ---------------------------------------------------------------------------
// Unified 128x128 bf16 MFMA GEMM: C[m,j] = sum_k A[m,k] * Bt[j,k]  (+epilogue)
// 512 threads = 8 waves (2x4), wave tile 64x32, acc 4x2 frags of 16x16.
// Single-buffer LDS, reg-staged, padded stride 72 (2-way bank alias = free).
// EPI: 0 = store bf16
//      1 = mul by vmul[m, gc] (V) then store bf16        (guided epilogue)
//      2 = +bias, exact gelu, store bf16                 (MLP hidden)
//      3 = +bias, store fp32                              (final output)
// AF32: A operand is fp32 (Ges) -> convert to bf16 during staging.
// ---------------------------------------------------------------------------
template<int EPI, bool AF32>
__global__ __launch_bounds__(512, 2) void gemm_k(
    const void* __restrict__ Ap, int lda,
    const u16* __restrict__ Bt, int ldb,
    void* __restrict__ Cp, int ldc, int K,
    const float* __restrict__ bias,
    const u16* __restrict__ vmul, int ldv)
{
    __shared__ u16 Asm[128 * 72];
    __shared__ u16 Bsm[128 * 72];

    const int t    = threadIdx.x;
    const int m0   = blockIdx.x * 128;
    const int n0   = blockIdx.y * 128;
    const int lane = t & 63;
    const int wid  = t >> 6;
    const int wr   = wid >> 2;       // 0..1
    const int wc   = wid & 3;        // 0..3
    const int lr   = lane & 15;
    const int lk   = (lane >> 4) * 8;

    f32x4 acc[4][2];
    #pragma unroll
    for (int i = 0; i < 4; ++i)
        #pragma unroll
        for (int j = 0; j < 2; ++j)
            acc[i][j] = (f32x4){0.f, 0.f, 0.f, 0.f};

    const int nsteps = K >> 6;
    for (int kt = 0; kt < nsteps; ++kt) {
        const int k0 = kt << 6;
        if (kt) __syncthreads();
        // ---- stage A tile (128 x 64) ----
        if constexpr (AF32) {
            const float* A32 = (const float*)Ap;
            #pragma unroll
            for (int p = 0; p < 4; ++p) {
                int q = p * 512 + t;
                int row = q >> 4, seg = q & 15;
                float4 v = *reinterpret_cast<const float4*>(
                    A32 + (size_t)(m0 + row) * (size_t)lda + k0 + seg * 4);
                ushort4 h;
                h.x = f2bf(v.x); h.y = f2bf(v.y); h.z = f2bf(v.z); h.w = f2bf(v.w);
                *reinterpret_cast<ushort4*>(&Asm[row * 72 + seg * 4]) = h;
            }
        } else {
            const u16* A16 = (const u16*)Ap;
            #pragma unroll
            for (int p = 0; p < 2; ++p) {
                int q = p * 512 + t;
                int row = q >> 3, seg = q & 7;
                uint4 v = *reinterpret_cast<const uint4*>(
                    A16 + (size_t)(m0 + row) * (size_t)lda + k0 + seg * 8);
                *reinterpret_cast<uint4*>(&Asm[row * 72 + seg * 8]) = v;
            }
        }
        // ---- stage Bt tile (128 x 64) ----
        #pragma unroll
        for (int p = 0; p < 2; ++p) {
            int q = p * 512 + t;
            int row = q >> 3, seg = q & 7;
            uint4 v = *reinterpret_cast<const uint4*>(
                Bt + (size_t)(n0 + row) * (size_t)ldb + k0 + seg * 8);
            *reinterpret_cast<uint4*>(&Bsm[row * 72 + seg * 8]) = v;
        }
        __syncthreads();
        // ---- MFMA ----
        #pragma unroll
        for (int kh = 0; kh < 2; ++kh) {
            const int kk = kh * 32;
            short8v a[4], b[2];
            #pragma unroll
            for (int i = 0; i < 4; ++i)
                a[i] = *reinterpret_cast<const short8v*>(
                    &Asm[(wr * 64 + i * 16 + lr) * 72 + kk + lk]);
            #pragma unroll
            for (int i = 0; i < 2; ++i)
                b[i] = *reinterpret_cast<const short8v*>(
                    &Bsm[(wc * 32 + i * 16 + lr) * 72 + kk + lk]);
            #pragma unroll
            for (int mi = 0; mi < 4; ++mi)
                #pragma unroll
                for (int ni = 0; ni < 2; ++ni)
                    acc[mi][ni] = __builtin_amdgcn_mfma_f32_16x16x32_bf16(
                        a[mi], b[ni], acc[mi][ni], 0, 0, 0);
        }
    }

    // ---- epilogue: C row = m from A-side, col = n from B-side ----
    #pragma unroll
    for (int mi = 0; mi < 4; ++mi) {
        #pragma unroll
        for (int ni = 0; ni < 2; ++ni) {
            const int gc = n0 + wc * 32 + ni * 16 + lr;
            #pragma unroll
            for (int j = 0; j < 4; ++j) {
                const int gr = m0 + wr * 64 + mi * 16 + (lane >> 4) * 4 + j;
                float v = acc[mi][ni][j];
                if constexpr (EPI == 0) {
                    ((u16*)Cp)[(size_t)gr * ldc + gc] = f2bf(v);
                } else if constexpr (EPI == 1) {
                    v *= bf2f(vmul[(size_t)gr * ldv + gc]);
                    ((u16*)Cp)[(size_t)gr * ldc + gc] = f2bf(v);
                } else if constexpr (EPI == 2) {
                    float x = v + bias[gc];
                    float g = 0.5f * x * (1.0f + erff(x * 0.70710678118f));
                    ((u16*)Cp)[(size_t)gr * ldc + gc] = f2bf(g);
                } else {
                    ((float*)Cp)[(size_t)gr * ldc + gc] = v + bias[gc];
                }
            }
        }
    }
}

// ---------------------------------------------------------------------------
// Convert x_in, Wq|Wk|Wv (concat), W1 to bf16 (vectorized grid-stride).
// ---------------------------------------------------------------------------
__global__ void k_convert(const float* __restrict__ x_in,
                          const float* __restrict__ Wq, const float* __restrict__ Wk,
                          const float* __restrict__ Wv, const float* __restrict__ W1,
                          u16* __restrict__ XB, u16* __restrict__ WqkvB,
                          u16* __restrict__ W1B)
{
    const int C1 = 1048576;              // x_in float4 chunks (8192*512/4)
    const int C2 = 196608;               // Wqkv chunks (3*512*512/4)
    const int C3 = 65536;                // W1 chunks
    for (int i = blockIdx.x * blockDim.x + threadIdx.x; i < C1 + C2 + C3;
         i += gridDim.x * blockDim.x) {
        const float* src; u16* dst;
        if (i < C1) { src = x_in + (size_t)i * 4; dst = XB + (size_t)i * 4; }
        else if (i < C1 + C2) {
            int e = (i - C1) * 4;
            if (e < 262144)      src = Wq + e;
            else if (e < 524288) src = Wk + (e - 262144);
            else                 src = Wv + (e - 524288);
            dst = WqkvB + e;
        } else {
            int e = (i - C1 - C2) * 4;
            src = W1 + e; dst = W1B + e;
        }
        float4 v = *reinterpret_cast<const float4*>(src);
        ushort4 h;
        h.x = f2bf(v.x); h.y = f2bf(v.y); h.z = f2bf(v.z); h.w = f2bf(v.w);
        *reinterpret_cast<ushort4*>(dst) = h;
    }
}

// ---------------------------------------------------------------------------
// TXT[c][m] = bf16(task_x[m][c])  — 64x64 tiles through LDS.
// ---------------------------------------------------------------------------
__global__ void k_transpose(const float* __restrict__ tx, u16* __restrict__ txt)
{
    __shared__ float tile[64][65];
    const int n0 = blockIdx.x * 64;
    const int c0 = blockIdx.y * 64;
    const int t = threadIdx.x;
    #pragma unroll
    for (int p = 0; p < 4; ++p) {
        int q = p * 256 + t;
        int r = q >> 4, s = q & 15;
        float4 v = *reinterpret_cast<const float4*>(tx + (size_t)(n0 + r) * 512 + c0 + s * 4);
        tile[r][s * 4 + 0] = v.x; tile[r][s * 4 + 1] = v.y;
        tile[r][s * 4 + 2] = v.z; tile[r][s * 4 + 3] = v.w;
    }
    __syncthreads();
    #pragma unroll
    for (int p = 0; p < 4; ++p) {
        int q = p * 256 + t;
        int cc = q >> 4, s = q & 15;
        ushort4 h;
        h.x = f2bf(tile[s * 4 + 0][cc]); h.y = f2bf(tile[s * 4 + 1][cc]);
        h.z = f2bf(tile[s * 4 + 2][cc]); h.w = f2bf(tile[s * 4 + 3][cc]);
        *reinterpret_cast<ushort4*>(txt + (size_t)(c0 + cc) * 8192 + n0 + s * 4) = h;
    }
}

// ---------------------------------------------------------------------------
// colsq[j] = sum_n QKV[n,j]^2 for j in [0,1024)  (Q cols 0..511, K cols 512..1023)
// ---------------------------------------------------------------------------
__global__ void k_colsq(const u16* __restrict__ QKV, float* __restrict__ colsq)
{
    const int t = threadIdx.x;
    const int c8 = t & 127, rs = t >> 7;
    float a[8];
    #pragma unroll
    for (int j = 0; j < 8; ++j) a[j] = 0.f;
    const int row0 = blockIdx.x * 64;
    for (int rr = rs; rr < 64; rr += 2) {
        uint4 u = *reinterpret_cast<const uint4*>(QKV + (size_t)(row0 + rr) * 1536 + c8 * 8);
        unsigned int w[4] = {u.x, u.y, u.z, u.w};
        #pragma unroll
        for (int q = 0; q < 4; ++q) {
            float f0 = bf2f((u16)(w[q] & 0xffffu));
            float f1 = bf2f((u16)(w[q] >> 16));
            a[2 * q]     += f0 * f0;
            a[2 * q + 1] += f1 * f1;
        }
    }
    #pragma unroll
    for (int j = 0; j < 8; ++j) atomicAdd(&colsq[c8 * 8 + j], a[j]);
}

// ---------------------------------------------------------------------------
// Per-head Gram partials: S[h,d,e] += sum_{n in chunk} K[n,h64+d]*Q[n,h64+e]
// grid = 8 heads x 16 row-chunks (512 rows each), 256 threads.
// ---------------------------------------------------------------------------
__global__ void k_gram(const u16* __restrict__ QKV, float* __restrict__ Sb)
{
    __shared__ u16 Qt[4][64];
    __shared__ u16 Kt[4][64];
    const int h = blockIdx.x >> 4;
    const int chunk = blockIdx.x & 15;
    const int t = threadIdx.x;
    const int e = t & 63;
    const int dg = t >> 6;               // wave id: d-group (uniform per wave)
    float acc[16];
    #pragma unroll
    for (int k = 0; k < 16; ++k) acc[k] = 0.f;
    const int rowbase = chunk * 512;
    for (int p = 0; p < 128; ++p) {
        __syncthreads();
        if (t < 64) {
            const int mat = t >> 5, sub = t & 31, r = sub >> 3, seg = sub & 7;
            const int row = rowbase + p * 4 + r;
            const int col = (mat ? 512 : 0) + h * 64 + seg * 8;
            uint4 v = *reinterpret_cast<const uint4*>(QKV + (size_t)row * 1536 + col);
            u16* dst = mat ? &Kt[r][seg * 8] : &Qt[r][seg * 8];
            *reinterpret_cast<uint4*>(dst) = v;
        }
        __syncthreads();
        #pragma unroll
        for (int r = 0; r < 4; ++r) {
            const float q = bf2f(Qt[r][e]);
            short8v kv0 = *reinterpret_cast<const short8v*>(&Kt[r][dg * 16]);
            short8v kv1 = *reinterpret_cast<const short8v*>(&Kt[r][dg * 16 + 8]);
            #pragma unroll
            for (int k = 0; k < 8; ++k) {
                acc[k]     += bf2f((u16)kv0[k]) * q;
                acc[k + 8] += bf2f((u16)kv1[k]) * q;
            }
        }
    }
    #pragma unroll
    for (int k = 0; k < 16; ++k)
        atomicAdd(&Sb[h * 4096 + (dg * 16 + k) * 64 + e], acc[k]);
}

// ---------------------------------------------------------------------------
// attn[h,d,e] = softmax_e( S/(||k_d|| ||q_e||) * rescale[h] )  -> Abuf fp32
// ---------------------------------------------------------------------------
__global__ void k_softmax(const float* __restrict__ Sb, const float* __restrict__ colsq,
                          const float* __restrict__ rescale, float* __restrict__ Abuf)
{
    const int h = blockIdx.x;
    const int t = threadIdx.x;   // 64
    const float rsc = rescale[h];
    const float nq = fmaxf(sqrtf(colsq[h * 64 + t]), 1e-12f);
    for (int d = 0; d < 64; ++d) {
        const float nk = fmaxf(sqrtf(colsq[512 + h * 64 + d]), 1e-12f);
        float v = Sb[h * 4096 + d * 64 + t] / (nk * nq) * rsc;
        float m = v;
        #pragma unroll
        for (int off = 32; off > 0; off >>= 1) m = fmaxf(m, __shfl_xor(m, off, 64));
        float p = expf(v - m);
        float s = p;
        #pragma unroll
        for (int off = 32; off > 0; off >>= 1) s += __shfl_xor(s, off, 64);
        Abuf[h * 4096 + d * 64 + t] = p / s;
    }
}

// ---------------------------------------------------------------------------
// BtC[j][c] for final GEMM:
//   c<512 :  M[c,j] = sum_d A[h_c,d,e_c] * Wp[j, h_c*64+d]    (attn folded w/ Wp)
//   c>=512:  W2[j][c-512]
// Also bsum[j] = bp[j] + b2[j].
// ---------------------------------------------------------------------------
__global__ void k_buildbt(const float* __restrict__ Abuf, const float* __restrict__ Wp,
                          const float* __restrict__ W2, const float* __restrict__ bp,
                          const float* __restrict__ b2, u16* __restrict__ BtC,
                          float* __restrict__ bsum)
{
    const int g = blockIdx.x * 256 + threadIdx.x;   // 524288 total
    const int j = g >> 10, c = g & 1023;
    if (c < 512) {
        const int h = c >> 6, e = c & 63;
        const float* Ah = Abuf + h * 4096 + e;
        const float* Wph = Wp + (size_t)j * 512 + h * 64;
        float s = 0.f;
        #pragma unroll 8
        for (int d = 0; d < 64; ++d) s += Ah[d * 64] * Wph[d];
        BtC[(size_t)j * 1024 + c] = f2bf(s);
        if (c == 0) bsum[j] = bp[j] + b2[j];
    } else {
        BtC[(size_t)j * 1024 + c] = f2bf(W2[(size_t)j * 512 + (c - 512)]);
    }
}

// ---------------------------------------------------------------------------
extern "C" void kernel_launch(void* const* d_in, const int* in_sizes, int n_in,
                              void* d_out, int out_size, void* d_ws, size_t ws_size,
                              hipStream_t stream)
{
    const float* x_in    = (const float*)d_in[0];
    const float* task_x  = (const float*)d_in[1];
    const float* Ges     = (const float*)d_in[2];
    const float* Wq      = (const float*)d_in[3];
    const float* Wk      = (const float*)d_in[4];
    const float* Wv      = (const float*)d_in[5];
    const float* rescale = (const float*)d_in[6];
    const float* Wp      = (const float*)d_in[7];
    const float* bp      = (const float*)d_in[8];
    const float* W1      = (const float*)d_in[9];
    const float* b1      = (const float*)d_in[10];
    const float* W2      = (const float*)d_in[11];
    const float* b2      = (const float*)d_in[12];
    float* out = (float*)d_out;
    char* ws = (char*)d_ws;

    // workspace layout (bytes)
    u16*   XB    = (u16*)  (ws + 0);            //  8192x512  bf16
    u16*   TXT   = (u16*)  (ws + 8388608);      //  512x8192  bf16 (task_x^T)
    u16*   QKV   = (u16*)  (ws + 16777216);     //  8192x1536 bf16 (Q|K|V)
    u16*   AH    = (u16*)  (ws + 41943040);     //  8192x1024 bf16 (guided|hidden)
    u16*   WqkvB = (u16*)  (ws + 58720256);     //  1536x512  bf16
    u16*   W1B   = (u16*)  (ws + 60293120);     //  512x512   bf16
    u16*   BtC   = (u16*)  (ws + 60817408);     //  512x1024  bf16
    float* colsq = (float*)(ws + 61865984);     //  1024 f32  (atomic-accumulated)
    float* Sb    = (float*)(ws + 61870080);     //  8x64x64 f32 (atomic-accumulated)
    float* Abuf  = (float*)(ws + 62001152);     //  8x64x64 f32
    float* bsum  = (float*)(ws + 62132224);     //  512 f32
    (void)in_sizes; (void)n_in; (void)out_size; (void)ws_size;

    // zero the atomic accumulators (colsq + Sb are contiguous)
    hipMemsetAsync(colsq, 0, 4096 + 131072, stream);

    k_convert  <<<2048, 256, 0, stream>>>(x_in, Wq, Wk, Wv, W1, XB, WqkvB, W1B);
    k_transpose<<<dim3(128, 8), 256, 0, stream>>>(task_x, TXT);

    // QKV = x @ [Wq;Wk;Wv]^T   (M=8192, N=1536, K=512)
    gemm_k<0, false><<<dim3(64, 12), 512, 0, stream>>>(
        XB, 512, WqkvB, 512, QKV, 1536, 512, nullptr, nullptr, 0);

    k_colsq  <<<128, 256, 0, stream>>>(QKV, colsq);
    k_gram   <<<128, 256, 0, stream>>>(QKV, Sb);
    k_softmax<<<8, 64, 0, stream>>>(Sb, colsq, rescale, Abuf);
    k_buildbt<<<2048, 256, 0, stream>>>(Abuf, Wp, W2, bp, b2, BtC, bsum);

    // guided = (Ges @ task_x) * V   (M=8192, N=512, K=8192; A is fp32)
    gemm_k<1, true><<<dim3(64, 4), 512, 0, stream>>>(
        Ges, 8192, TXT, 8192, AH, 1024, 8192, nullptr, QKV + 1024, 1536);

    // hidden = gelu(V @ W1^T + b1)  (M=8192, N=512, K=512)
    gemm_k<2, false><<<dim3(64, 4), 512, 0, stream>>>(
        QKV + 1024, 1536, W1B, 512, AH + 512, 1024, 512, b1, nullptr, 0);

    // out = [guided|hidden] @ BtC^T + (bp+b2)  (M=8192, N=512, K=1024)
    gemm_k<3, false><<<dim3(64, 4), 512, 0, stream>>>(
        AH, 1024, BtC, 1024, out, 512, 1024, bsum, nullptr, 0);
}

// Round 2
// 371.321 us; speedup vs baseline: 1.5544x; 1.5544x over previous
//
#include <hip/hip_runtime.h>
#include <hip/hip_bf16.h>

typedef unsigned short u16;
typedef __attribute__((ext_vector_type(8))) short short8v;
typedef __attribute__((ext_vector_type(4))) float f32x4;

typedef __attribute__((address_space(3))) char lds_char;
typedef const __attribute__((address_space(1))) char g_char;

__device__ __forceinline__ u16 f2bf(float f) {
    union { float f; unsigned int u; } x; x.f = f;
    unsigned int u = x.u;
    unsigned int r = (u + 0x7FFFu + ((u >> 16) & 1u)) >> 16;
    return (u16)r;
}
__device__ __forceinline__ float bf2f(u16 h) {
    union { unsigned int u; float f; } x; x.u = ((unsigned int)h) << 16;
    return x.f;
}
__device__ __forceinline__ void gload16(const void* g, void* l) {
    __builtin_amdgcn_global_load_lds((g_char*)g, (lds_char*)l, 16, 0, 0);
}

// ---------------------------------------------------------------------------
// 128x128 bf16 MFMA GEMM, BK=64, 512 thr = 8 waves (2x4), wave tile 64x32.
// 2-phase double-buffered LDS, global_load_lds(16B) staging, XOR-swizzled
// LDS layout (pre-swizzled global source, swizzled ds_read).
// EPI: 0=store bf16, 1=*V store bf16, 2=+bias,gelu store bf16, 3=+bias f32.
// AF32: A operand fp32 (Ges) staged as fp32, converted on fragment path.
// ---------------------------------------------------------------------------
template<int EPI, bool AF32>
__global__ __launch_bounds__(512, (AF32 ? 2 : 4)) void gemm_k(
    const void* __restrict__ Ap, int lda,
    const u16* __restrict__ Bt, int ldb,
    void* __restrict__ Cp, int ldc, int K,
    const float* __restrict__ bias,
    const u16* __restrict__ vmul, int ldv)
{
    constexpr int ATB = AF32 ? 32768 : 16384;   // A tile bytes
    constexpr int BTB = 16384;                  // B tile bytes
    __shared__ alignas(16) char smem[2 * (ATB + BTB)];

    const int t    = threadIdx.x;
    const int m0   = blockIdx.x * 128;
    const int n0   = blockIdx.y * 128;
    const int lane = t & 63;
    const int wid  = t >> 6;
    const int wr   = wid >> 2;       // 0..1
    const int wc   = wid & 3;        // 0..3
    const int lr   = lane & 15;
    const int q4   = lane >> 4;      // 0..3

    f32x4 acc[4][2];
    #pragma unroll
    for (int i = 0; i < 4; ++i)
        #pragma unroll
        for (int j = 0; j < 2; ++j)
            acc[i][j] = (f32x4){0.f, 0.f, 0.f, 0.f};

    // ---- staging: issue global_load_lds for tile kt into buffer b ----
    auto stage = [&](int b, int kt) {
        const int k0 = kt << 6;
        char* base = smem + b * (ATB + BTB);
        if constexpr (AF32) {
            const float* A32 = (const float*)Ap;
            #pragma unroll
            for (int r = 0; r < 4; ++r) {
                int o   = r * 8192 + t * 16;
                int row = o >> 8;
                int cb  = (o & 255) ^ ((row & 15) << 4);   // inverse swizzle
                const float* gp = A32 + (size_t)(m0 + row) * (size_t)lda + k0 + (cb >> 2);
                gload16(gp, base + r * 8192 + wid * 1024);
            }
        } else {
            const u16* A16 = (const u16*)Ap;
            #pragma unroll
            for (int r = 0; r < 2; ++r) {
                int o   = r * 8192 + t * 16;
                int row = o >> 7;
                int cb  = (o & 127) ^ ((row & 7) << 4);
                const u16* gp = A16 + (size_t)(m0 + row) * (size_t)lda + k0 + (cb >> 1);
                gload16(gp, base + r * 8192 + wid * 1024);
            }
        }
        char* bb = base + ATB;
        #pragma unroll
        for (int r = 0; r < 2; ++r) {
            int o   = r * 8192 + t * 16;
            int row = o >> 7;
            int cb  = (o & 127) ^ ((row & 7) << 4);
            const u16* gp = Bt + (size_t)(n0 + row) * (size_t)ldb + k0 + (cb >> 1);
            gload16(gp, bb + r * 8192 + wid * 1024);
        }
    };

    // ---- compute one K-step from buffer b ----
    auto compute = [&](int b) {
        char* base = smem + b * (ATB + BTB);
        char* bb = base + ATB;
        #pragma unroll
        for (int kh = 0; kh < 2; ++kh) {
            short8v a[4], bf[2];
            #pragma unroll
            for (int mi = 0; mi < 4; ++mi) {
                const int ar = wr * 64 + mi * 16 + lr;
                if constexpr (AF32) {
                    const int cb0 = kh * 128 + q4 * 32;
                    const int c0 = cb0 ^ ((ar & 15) << 4);
                    const int c1 = (cb0 + 16) ^ ((ar & 15) << 4);
                    f32x4 f0 = *(const f32x4*)(base + ar * 256 + c0);
                    f32x4 f1 = *(const f32x4*)(base + ar * 256 + c1);
                    short8v av;
                    #pragma unroll
                    for (int j = 0; j < 4; ++j) {
                        av[j]     = (short)__builtin_bit_cast(u16, __float2bfloat16(f0[j]));
                        av[j + 4] = (short)__builtin_bit_cast(u16, __float2bfloat16(f1[j]));
                    }
                    a[mi] = av;
                } else {
                    const int cb = kh * 64 + q4 * 16;
                    const int cp = cb ^ ((ar & 7) << 4);
                    a[mi] = *(const short8v*)(base + ar * 128 + cp);
                }
            }
            #pragma unroll
            for (int ni = 0; ni < 2; ++ni) {
                const int br = wc * 32 + ni * 16 + lr;
                const int cb = kh * 64 + q4 * 16;
                const int cp = cb ^ ((br & 7) << 4);
                bf[ni] = *(const short8v*)(bb + br * 128 + cp);
            }
            #pragma unroll
            for (int mi = 0; mi < 4; ++mi)
                #pragma unroll
                for (int ni = 0; ni < 2; ++ni)
                    acc[mi][ni] = __builtin_amdgcn_mfma_f32_16x16x32_bf16(
                        a[mi], bf[ni], acc[mi][ni], 0, 0, 0);
        }
    };

    const int nsteps = K >> 6;
    stage(0, 0);
    __syncthreads();                    // vmcnt(0) drain -> tile 0 ready
    int cur = 0;
    for (int kt = 0; kt < nsteps; ++kt) {
        if (kt + 1 < nsteps) stage(cur ^ 1, kt + 1);   // prefetch overlaps compute
        compute(cur);
        __syncthreads();                // drains prefetch + readers of cur
        cur ^= 1;
    }

    // ---- epilogue ----
    #pragma unroll
    for (int mi = 0; mi < 4; ++mi) {
        #pragma unroll
        for (int ni = 0; ni < 2; ++ni) {
            const int gc = n0 + wc * 32 + ni * 16 + lr;
            #pragma unroll
            for (int j = 0; j < 4; ++j) {
                const int gr = m0 + wr * 64 + mi * 16 + q4 * 4 + j;
                float v = acc[mi][ni][j];
                if constexpr (EPI == 0) {
                    ((u16*)Cp)[(size_t)gr * ldc + gc] = f2bf(v);
                } else if constexpr (EPI == 1) {
                    v *= bf2f(vmul[(size_t)gr * ldv + gc]);
                    ((u16*)Cp)[(size_t)gr * ldc + gc] = f2bf(v);
                } else if constexpr (EPI == 2) {
                    float x = v + bias[gc];
                    float g = 0.5f * x * (1.0f + erff(x * 0.70710678118f));
                    ((u16*)Cp)[(size_t)gr * ldc + gc] = f2bf(g);
                } else {
                    ((float*)Cp)[(size_t)gr * ldc + gc] = v + bias[gc];
                }
            }
        }
    }
}

// ---------------------------------------------------------------------------
// Convert x_in, Wq|Wk|Wv (concat), W1 to bf16 (vectorized grid-stride).
// ---------------------------------------------------------------------------
__global__ void k_convert(const float* __restrict__ x_in,
                          const float* __restrict__ Wq, const float* __restrict__ Wk,
                          const float* __restrict__ Wv, const float* __restrict__ W1,
                          u16* __restrict__ XB, u16* __restrict__ WqkvB,
                          u16* __restrict__ W1B)
{
    const int C1 = 1048576;
    const int C2 = 196608;
    const int C3 = 65536;
    for (int i = blockIdx.x * blockDim.x + threadIdx.x; i < C1 + C2 + C3;
         i += gridDim.x * blockDim.x) {
        const float* src; u16* dst;
        if (i < C1) { src = x_in + (size_t)i * 4; dst = XB + (size_t)i * 4; }
        else if (i < C1 + C2) {
            int e = (i - C1) * 4;
            if (e < 262144)      src = Wq + e;
            else if (e < 524288) src = Wk + (e - 262144);
            else                 src = Wv + (e - 524288);
            dst = WqkvB + e;
        } else {
            int e = (i - C1 - C2) * 4;
            src = W1 + e; dst = W1B + e;
        }
        float4 v = *reinterpret_cast<const float4*>(src);
        ushort4 h;
        h.x = f2bf(v.x); h.y = f2bf(v.y); h.z = f2bf(v.z); h.w = f2bf(v.w);
        *reinterpret_cast<ushort4*>(dst) = h;
    }
}

// ---------------------------------------------------------------------------
// TXT[c][m] = bf16(task_x[m][c])  — 64x64 tiles through LDS.
// ---------------------------------------------------------------------------
__global__ void k_transpose(const float* __restrict__ tx, u16* __restrict__ txt)
{
    __shared__ float tile[64][65];
    const int n0 = blockIdx.x * 64;
    const int c0 = blockIdx.y * 64;
    const int t = threadIdx.x;
    #pragma unroll
    for (int p = 0; p < 4; ++p) {
        int q = p * 256 + t;
        int r = q >> 4, s = q & 15;
        float4 v = *reinterpret_cast<const float4*>(tx + (size_t)(n0 + r) * 512 + c0 + s * 4);
        tile[r][s * 4 + 0] = v.x; tile[r][s * 4 + 1] = v.y;
        tile[r][s * 4 + 2] = v.z; tile[r][s * 4 + 3] = v.w;
    }
    __syncthreads();
    #pragma unroll
    for (int p = 0; p < 4; ++p) {
        int q = p * 256 + t;
        int cc = q >> 4, s = q & 15;
        ushort4 h;
        h.x = f2bf(tile[s * 4 + 0][cc]); h.y = f2bf(tile[s * 4 + 1][cc]);
        h.z = f2bf(tile[s * 4 + 2][cc]); h.w = f2bf(tile[s * 4 + 3][cc]);
        *reinterpret_cast<ushort4*>(txt + (size_t)(c0 + cc) * 8192 + n0 + s * 4) = h;
    }
}

// ---------------------------------------------------------------------------
// colsq[j] = sum_n QKV[n,j]^2, j in [0,1024)
// ---------------------------------------------------------------------------
__global__ void k_colsq(const u16* __restrict__ QKV, float* __restrict__ colsq)
{
    const int t = threadIdx.x;
    const int c8 = t & 127, rs = t >> 7;
    float a[8];
    #pragma unroll
    for (int j = 0; j < 8; ++j) a[j] = 0.f;
    const int row0 = blockIdx.x * 64;
    for (int rr = rs; rr < 64; rr += 2) {
        uint4 u = *reinterpret_cast<const uint4*>(QKV + (size_t)(row0 + rr) * 1536 + c8 * 8);
        unsigned int w[4] = {u.x, u.y, u.z, u.w};
        #pragma unroll
        for (int q = 0; q < 4; ++q) {
            float f0 = bf2f((u16)(w[q] & 0xffffu));
            float f1 = bf2f((u16)(w[q] >> 16));
            a[2 * q]     += f0 * f0;
            a[2 * q + 1] += f1 * f1;
        }
    }
    #pragma unroll
    for (int j = 0; j < 8; ++j) atomicAdd(&colsq[c8 * 8 + j], a[j]);
}

// ---------------------------------------------------------------------------
// Per-head Gram partials: S[h,d,e] += sum_{n in chunk} K[n,h64+d]*Q[n,h64+e]
// grid = 8 heads x 64 row-chunks (128 rows each), 256 threads.
// ---------------------------------------------------------------------------
__global__ void k_gram(const u16* __restrict__ QKV, float* __restrict__ Sb)
{
    __shared__ u16 Qt[4][64];
    __shared__ u16 Kt[4][64];
    const int h = blockIdx.x >> 6;
    const int chunk = blockIdx.x & 63;
    const int t = threadIdx.x;
    const int e = t & 63;
    const int dg = t >> 6;
    float acc[16];
    #pragma unroll
    for (int k = 0; k < 16; ++k) acc[k] = 0.f;
    const int rowbase = chunk * 128;
    for (int p = 0; p < 32; ++p) {
        __syncthreads();
        if (t < 64) {
            const int mat = t >> 5, sub = t & 31, r = sub >> 3, seg = sub & 7;
            const int row = rowbase + p * 4 + r;
            const int col = (mat ? 512 : 0) + h * 64 + seg * 8;
            uint4 v = *reinterpret_cast<const uint4*>(QKV + (size_t)row * 1536 + col);
            u16* dst = mat ? &Kt[r][seg * 8] : &Qt[r][seg * 8];
            *reinterpret_cast<uint4*>(dst) = v;
        }
        __syncthreads();
        #pragma unroll
        for (int r = 0; r < 4; ++r) {
            const float q = bf2f(Qt[r][e]);
            short8v kv0 = *reinterpret_cast<const short8v*>(&Kt[r][dg * 16]);
            short8v kv1 = *reinterpret_cast<const short8v*>(&Kt[r][dg * 16 + 8]);
            #pragma unroll
            for (int k = 0; k < 8; ++k) {
                acc[k]     += bf2f((u16)kv0[k]) * q;
                acc[k + 8] += bf2f((u16)kv1[k]) * q;
            }
        }
    }
    #pragma unroll
    for (int k = 0; k < 16; ++k)
        atomicAdd(&Sb[h * 4096 + (dg * 16 + k) * 64 + e], acc[k]);
}

// ---------------------------------------------------------------------------
// attn[h,d,e] = softmax_e( S/(||k_d|| ||q_e||) * rescale[h] )
// ---------------------------------------------------------------------------
__global__ void k_softmax(const float* __restrict__ Sb, const float* __restrict__ colsq,
                          const float* __restrict__ rescale, float* __restrict__ Abuf)
{
    const int h = blockIdx.x;
    const int t = threadIdx.x;   // 64
    const float rsc = rescale[h];
    const float nq = fmaxf(sqrtf(colsq[h * 64 + t]), 1e-12f);
    for (int d = 0; d < 64; ++d) {
        const float nk = fmaxf(sqrtf(colsq[512 + h * 64 + d]), 1e-12f);
        float v = Sb[h * 4096 + d * 64 + t] / (nk * nq) * rsc;
        float m = v;
        #pragma unroll
        for (int off = 32; off > 0; off >>= 1) m = fmaxf(m, __shfl_xor(m, off, 64));
        float p = expf(v - m);
        float s = p;
        #pragma unroll
        for (int off = 32; off > 0; off >>= 1) s += __shfl_xor(s, off, 64);
        Abuf[h * 4096 + d * 64 + t] = p / s;
    }
}

// ---------------------------------------------------------------------------
// BtC[j][c]: c<512 -> fold attn with Wp; c>=512 -> W2. bsum[j] = bp[j]+b2[j].
// ---------------------------------------------------------------------------
__global__ void k_buildbt(const float* __restrict__ Abuf, const float* __restrict__ Wp,
                          const float* __restrict__ W2, const float* __restrict__ bp,
                          const float* __restrict__ b2, u16* __restrict__ BtC,
                          float* __restrict__ bsum)
{
    const int g = blockIdx.x * 256 + threadIdx.x;
    const int j = g >> 10, c = g & 1023;
    if (c < 512) {
        const int h = c >> 6, e = c & 63;
        const float* Ah = Abuf + h * 4096 + e;
        const float* Wph = Wp + (size_t)j * 512 + h * 64;
        float s = 0.f;
        #pragma unroll 8
        for (int d = 0; d < 64; ++d) s += Ah[d * 64] * Wph[d];
        BtC[(size_t)j * 1024 + c] = f2bf(s);
        if (c == 0) bsum[j] = bp[j] + b2[j];
    } else {
        BtC[(size_t)j * 1024 + c] = f2bf(W2[(size_t)j * 512 + (c - 512)]);
    }
}

// ---------------------------------------------------------------------------
extern "C" void kernel_launch(void* const* d_in, const int* in_sizes, int n_in,
                              void* d_out, int out_size, void* d_ws, size_t ws_size,
                              hipStream_t stream)
{
    const float* x_in    = (const float*)d_in[0];
    const float* task_x  = (const float*)d_in[1];
    const float* Ges     = (const float*)d_in[2];
    const float* Wq      = (const float*)d_in[3];
    const float* Wk      = (const float*)d_in[4];
    const float* Wv      = (const float*)d_in[5];
    const float* rescale = (const float*)d_in[6];
    const float* Wp      = (const float*)d_in[7];
    const float* bp      = (const float*)d_in[8];
    const float* W1      = (const float*)d_in[9];
    const float* b1      = (const float*)d_in[10];
    const float* W2      = (const float*)d_in[11];
    const float* b2      = (const float*)d_in[12];
    float* out = (float*)d_out;
    char* ws = (char*)d_ws;

    u16*   XB    = (u16*)  (ws + 0);            //  8192x512  bf16
    u16*   TXT   = (u16*)  (ws + 8388608);      //  512x8192  bf16
    u16*   QKV   = (u16*)  (ws + 16777216);     //  8192x1536 bf16
    u16*   AH    = (u16*)  (ws + 41943040);     //  8192x1024 bf16
    u16*   WqkvB = (u16*)  (ws + 58720256);     //  1536x512  bf16
    u16*   W1B   = (u16*)  (ws + 60293120);     //  512x512   bf16
    u16*   BtC   = (u16*)  (ws + 60817408);     //  512x1024  bf16
    float* colsq = (float*)(ws + 61865984);     //  1024 f32
    float* Sb    = (float*)(ws + 61870080);     //  8x64x64 f32
    float* Abuf  = (float*)(ws + 62001152);     //  8x64x64 f32
    float* bsum  = (float*)(ws + 62132224);     //  512 f32
    (void)in_sizes; (void)n_in; (void)out_size; (void)ws_size;

    hipMemsetAsync(colsq, 0, 4096 + 131072, stream);

    k_convert  <<<2048, 256, 0, stream>>>(x_in, Wq, Wk, Wv, W1, XB, WqkvB, W1B);
    k_transpose<<<dim3(128, 8), 256, 0, stream>>>(task_x, TXT);

    // QKV = x @ [Wq;Wk;Wv]^T   (M=8192, N=1536, K=512)
    gemm_k<0, false><<<dim3(64, 12), 512, 0, stream>>>(
        XB, 512, WqkvB, 512, QKV, 1536, 512, nullptr, nullptr, 0);

    k_colsq  <<<128, 256, 0, stream>>>(QKV, colsq);
    k_gram   <<<512, 256, 0, stream>>>(QKV, Sb);
    k_softmax<<<8, 64, 0, stream>>>(Sb, colsq, rescale, Abuf);
    k_buildbt<<<2048, 256, 0, stream>>>(Abuf, Wp, W2, bp, b2, BtC, bsum);

    // guided = (Ges @ task_x) * V   (M=8192, N=512, K=8192; A fp32)
    gemm_k<1, true><<<dim3(64, 4), 512, 0, stream>>>(
        Ges, 8192, TXT, 8192, AH, 1024, 8192, nullptr, QKV + 1024, 1536);

    // hidden = gelu(V @ W1^T + b1)  (M=8192, N=512, K=512)
    gemm_k<2, false><<<dim3(64, 4), 512, 0, stream>>>(
        QKV + 1024, 1536, W1B, 512, AH + 512, 1024, 512, b1, nullptr, 0);

    // out = [guided|hidden] @ BtC^T + (bp+b2)  (M=8192, N=512, K=1024)
    gemm_k<3, false><<<dim3(64, 4), 512, 0, stream>>>(
        AH, 1024, BtC, 1024, out, 512, 1024, bsum, nullptr, 0);
}

// Round 3
// 339.040 us; speedup vs baseline: 1.7024x; 1.0952x over previous
//
#include <hip/hip_runtime.h>
#include <hip/hip_bf16.h>

typedef unsigned short u16;
typedef __attribute__((ext_vector_type(8))) short short8v;
typedef __attribute__((ext_vector_type(4))) float f32x4;

typedef __attribute__((address_space(3))) char lds_char;
typedef const __attribute__((address_space(1))) char g_char;

__device__ __forceinline__ u16 f2bf(float f) {
    union { float f; unsigned int u; } x; x.f = f;
    unsigned int u = x.u;
    unsigned int r = (u + 0x7FFFu + ((u >> 16) & 1u)) >> 16;
    return (u16)r;
}
__device__ __forceinline__ float bf2f(u16 h) {
    union { unsigned int u; float f; } x; x.u = ((unsigned int)h) << 16;
    return x.f;
}
__device__ __forceinline__ void gload16(const void* g, void* l) {
    __builtin_amdgcn_global_load_lds((g_char*)g, (lds_char*)l, 16, 0, 0);
}
template<int N> __device__ __forceinline__ void vm_wait() {
    asm volatile("s_waitcnt vmcnt(%0)" :: "i"(N) : "memory");
}
__device__ __forceinline__ void barrier_raw() {
    __builtin_amdgcn_sched_barrier(0);
    __builtin_amdgcn_s_barrier();
    __builtin_amdgcn_sched_barrier(0);
}

// ---------------------------------------------------------------------------
// 128x128 bf16 MFMA GEMM, BK=64, 512 thr = 8 waves (2x4), wave tile 64x32.
// DEPTH-buffered LDS (3 for AF32, 2 for bf16), global_load_lds(16B) staging,
// counted-vmcnt pipeline with raw s_barrier (loads stay in flight across
// barriers — never vmcnt(0) in the main loop). XOR-swizzled LDS layout.
// EPI: 0=store bf16, 1=*V store bf16, 2=+bias,gelu store bf16, 3=+bias f32.
// AF32: A operand fp32 (Ges) staged as fp32, converted on fragment path.
// ---------------------------------------------------------------------------
template<int EPI, bool AF32>
__global__ __launch_bounds__(512, (AF32 ? 2 : 4)) void gemm_k(
    const void* __restrict__ Ap, int lda,
    const u16* __restrict__ Bt, int ldb,
    void* __restrict__ Cp, int ldc, int K,
    const float* __restrict__ bias,
    const u16* __restrict__ vmul, int ldv)
{
    constexpr int ATB   = AF32 ? 32768 : 16384;   // A tile bytes
    constexpr int BTB   = 16384;                  // B tile bytes
    constexpr int DEPTH = AF32 ? 3 : 2;           // pipeline depth (LDS bufs)
    constexpr int LPS   = AF32 ? 6 : 4;           // gload16 per thread per stage
    __shared__ alignas(16) char smem[DEPTH * (ATB + BTB)];

    const int t    = threadIdx.x;
    const int m0   = blockIdx.x * 128;
    const int n0   = blockIdx.y * 128;
    const int lane = t & 63;
    const int wid  = t >> 6;
    const int wr   = wid >> 2;       // 0..1
    const int wc   = wid & 3;        // 0..3
    const int lr   = lane & 15;
    const int q4   = lane >> 4;      // 0..3

    f32x4 acc[4][2];
    #pragma unroll
    for (int i = 0; i < 4; ++i)
        #pragma unroll
        for (int j = 0; j < 2; ++j)
            acc[i][j] = (f32x4){0.f, 0.f, 0.f, 0.f};

    // ---- staging: issue global_load_lds for tile kt into buffer b ----
    auto stage = [&](int b, int kt) {
        const int k0 = kt << 6;
        char* base = smem + b * (ATB + BTB);
        if constexpr (AF32) {
            const float* A32 = (const float*)Ap;
            #pragma unroll
            for (int r = 0; r < 4; ++r) {
                int o   = r * 8192 + t * 16;
                int row = o >> 8;
                int cb  = (o & 255) ^ ((row & 15) << 4);   // inverse swizzle
                const float* gp = A32 + (size_t)(m0 + row) * (size_t)lda + k0 + (cb >> 2);
                gload16(gp, base + r * 8192 + wid * 1024);
            }
        } else {
            const u16* A16 = (const u16*)Ap;
            #pragma unroll
            for (int r = 0; r < 2; ++r) {
                int o   = r * 8192 + t * 16;
                int row = o >> 7;
                int cb  = (o & 127) ^ ((row & 7) << 4);
                const u16* gp = A16 + (size_t)(m0 + row) * (size_t)lda + k0 + (cb >> 1);
                gload16(gp, base + r * 8192 + wid * 1024);
            }
        }
        char* bb = base + ATB;
        #pragma unroll
        for (int r = 0; r < 2; ++r) {
            int o   = r * 8192 + t * 16;
            int row = o >> 7;
            int cb  = (o & 127) ^ ((row & 7) << 4);
            const u16* gp = Bt + (size_t)(n0 + row) * (size_t)ldb + k0 + (cb >> 1);
            gload16(gp, bb + r * 8192 + wid * 1024);
        }
    };

    // ---- compute one K-step from buffer b ----
    auto compute = [&](int b) {
        char* base = smem + b * (ATB + BTB);
        char* bb = base + ATB;
        #pragma unroll
        for (int kh = 0; kh < 2; ++kh) {
            short8v a[4], bf[2];
            #pragma unroll
            for (int mi = 0; mi < 4; ++mi) {
                const int ar = wr * 64 + mi * 16 + lr;
                if constexpr (AF32) {
                    const int cb0 = kh * 128 + q4 * 32;
                    const int c0 = cb0 ^ ((ar & 15) << 4);
                    const int c1 = (cb0 + 16) ^ ((ar & 15) << 4);
                    f32x4 f0 = *(const f32x4*)(base + ar * 256 + c0);
                    f32x4 f1 = *(const f32x4*)(base + ar * 256 + c1);
                    short8v av;
                    #pragma unroll
                    for (int j = 0; j < 4; ++j) {
                        av[j]     = (short)__builtin_bit_cast(u16, __float2bfloat16(f0[j]));
                        av[j + 4] = (short)__builtin_bit_cast(u16, __float2bfloat16(f1[j]));
                    }
                    a[mi] = av;
                } else {
                    const int cb = kh * 64 + q4 * 16;
                    const int cp = cb ^ ((ar & 7) << 4);
                    a[mi] = *(const short8v*)(base + ar * 128 + cp);
                }
            }
            #pragma unroll
            for (int ni = 0; ni < 2; ++ni) {
                const int br = wc * 32 + ni * 16 + lr;
                const int cb = kh * 64 + q4 * 16;
                const int cp = cb ^ ((br & 7) << 4);
                bf[ni] = *(const short8v*)(bb + br * 128 + cp);
            }
            #pragma unroll
            for (int mi = 0; mi < 4; ++mi)
                #pragma unroll
                for (int ni = 0; ni < 2; ++ni)
                    acc[mi][ni] = __builtin_amdgcn_mfma_f32_16x16x32_bf16(
                        a[mi], bf[ni], acc[mi][ni], 0, 0, 0);
        }
    };

    const int nsteps = K >> 6;   // callers guarantee nsteps >= DEPTH
    #pragma unroll
    for (int d = 0; d < DEPTH; ++d) stage(d, d);

    int cur = 0;
    for (int kt = 0; kt + DEPTH < nsteps; ++kt) {
        vm_wait<LPS * (DEPTH - 1)>();   // tile kt ready; DEPTH-1 stages in flight
        barrier_raw();
        compute(cur);
        barrier_raw();                  // all waves done reading buf[cur]
        stage(cur, kt + DEPTH);
        cur = (cur + 1 == DEPTH) ? 0 : cur + 1;
    }
    // tail: DEPTH drain iterations
    if constexpr (DEPTH == 3) {
        vm_wait<2 * LPS>(); barrier_raw(); compute(cur); barrier_raw();
        cur = (cur + 1 == DEPTH) ? 0 : cur + 1;
        vm_wait<LPS>();     barrier_raw(); compute(cur); barrier_raw();
        cur = (cur + 1 == DEPTH) ? 0 : cur + 1;
        vm_wait<0>();       barrier_raw(); compute(cur);
    } else {
        vm_wait<LPS>(); barrier_raw(); compute(cur); barrier_raw();
        cur ^= 1;
        vm_wait<0>();   barrier_raw(); compute(cur);
    }

    // ---- epilogue ----
    #pragma unroll
    for (int mi = 0; mi < 4; ++mi) {
        #pragma unroll
        for (int ni = 0; ni < 2; ++ni) {
            const int gc = n0 + wc * 32 + ni * 16 + lr;
            #pragma unroll
            for (int j = 0; j < 4; ++j) {
                const int gr = m0 + wr * 64 + mi * 16 + q4 * 4 + j;
                float v = acc[mi][ni][j];
                if constexpr (EPI == 0) {
                    ((u16*)Cp)[(size_t)gr * ldc + gc] = f2bf(v);
                } else if constexpr (EPI == 1) {
                    v *= bf2f(vmul[(size_t)gr * ldv + gc]);
                    ((u16*)Cp)[(size_t)gr * ldc + gc] = f2bf(v);
                } else if constexpr (EPI == 2) {
                    float x = v + bias[gc];
                    float g = 0.5f * x * (1.0f + erff(x * 0.70710678118f));
                    ((u16*)Cp)[(size_t)gr * ldc + gc] = f2bf(g);
                } else {
                    ((float*)Cp)[(size_t)gr * ldc + gc] = v + bias[gc];
                }
            }
        }
    }
}

// ---------------------------------------------------------------------------
// Convert x_in, Wq|Wk|Wv (concat), W1 to bf16 (vectorized grid-stride).
// ---------------------------------------------------------------------------
__global__ void k_convert(const float* __restrict__ x_in,
                          const float* __restrict__ Wq, const float* __restrict__ Wk,
                          const float* __restrict__ Wv, const float* __restrict__ W1,
                          u16* __restrict__ XB, u16* __restrict__ WqkvB,
                          u16* __restrict__ W1B)
{
    const int C1 = 1048576;
    const int C2 = 196608;
    const int C3 = 65536;
    for (int i = blockIdx.x * blockDim.x + threadIdx.x; i < C1 + C2 + C3;
         i += gridDim.x * blockDim.x) {
        const float* src; u16* dst;
        if (i < C1) { src = x_in + (size_t)i * 4; dst = XB + (size_t)i * 4; }
        else if (i < C1 + C2) {
            int e = (i - C1) * 4;
            if (e < 262144)      src = Wq + e;
            else if (e < 524288) src = Wk + (e - 262144);
            else                 src = Wv + (e - 524288);
            dst = WqkvB + e;
        } else {
            int e = (i - C1 - C2) * 4;
            src = W1 + e; dst = W1B + e;
        }
        float4 v = *reinterpret_cast<const float4*>(src);
        ushort4 h;
        h.x = f2bf(v.x); h.y = f2bf(v.y); h.z = f2bf(v.z); h.w = f2bf(v.w);
        *reinterpret_cast<ushort4*>(dst) = h;
    }
}

// ---------------------------------------------------------------------------
// TXT[c][m] = bf16(task_x[m][c])  — 64x64 tiles through LDS.
// ---------------------------------------------------------------------------
__global__ void k_transpose(const float* __restrict__ tx, u16* __restrict__ txt)
{
    __shared__ float tile[64][65];
    const int n0 = blockIdx.x * 64;
    const int c0 = blockIdx.y * 64;
    const int t = threadIdx.x;
    #pragma unroll
    for (int p = 0; p < 4; ++p) {
        int q = p * 256 + t;
        int r = q >> 4, s = q & 15;
        float4 v = *reinterpret_cast<const float4*>(tx + (size_t)(n0 + r) * 512 + c0 + s * 4);
        tile[r][s * 4 + 0] = v.x; tile[r][s * 4 + 1] = v.y;
        tile[r][s * 4 + 2] = v.z; tile[r][s * 4 + 3] = v.w;
    }
    __syncthreads();
    #pragma unroll
    for (int p = 0; p < 4; ++p) {
        int q = p * 256 + t;
        int cc = q >> 4, s = q & 15;
        ushort4 h;
        h.x = f2bf(tile[s * 4 + 0][cc]); h.y = f2bf(tile[s * 4 + 1][cc]);
        h.z = f2bf(tile[s * 4 + 2][cc]); h.w = f2bf(tile[s * 4 + 3][cc]);
        *reinterpret_cast<ushort4*>(txt + (size_t)(c0 + cc) * 8192 + n0 + s * 4) = h;
    }
}

// ---------------------------------------------------------------------------
// colsq[j] = sum_n QKV[n,j]^2, j in [0,1024)
// ---------------------------------------------------------------------------
__global__ void k_colsq(const u16* __restrict__ QKV, float* __restrict__ colsq)
{
    const int t = threadIdx.x;
    const int c8 = t & 127, rs = t >> 7;
    float a[8];
    #pragma unroll
    for (int j = 0; j < 8; ++j) a[j] = 0.f;
    const int row0 = blockIdx.x * 64;
    for (int rr = rs; rr < 64; rr += 2) {
        uint4 u = *reinterpret_cast<const uint4*>(QKV + (size_t)(row0 + rr) * 1536 + c8 * 8);
        unsigned int w[4] = {u.x, u.y, u.z, u.w};
        #pragma unroll
        for (int q = 0; q < 4; ++q) {
            float f0 = bf2f((u16)(w[q] & 0xffffu));
            float f1 = bf2f((u16)(w[q] >> 16));
            a[2 * q]     += f0 * f0;
            a[2 * q + 1] += f1 * f1;
        }
    }
    #pragma unroll
    for (int j = 0; j < 8; ++j) atomicAdd(&colsq[c8 * 8 + j], a[j]);
}

// ---------------------------------------------------------------------------
// Per-head Gram partials: S[h,d,e] += sum_{n in chunk} K[n,h64+d]*Q[n,h64+e]
// grid = 8 heads x 64 row-chunks (128 rows each), 256 threads.
// ---------------------------------------------------------------------------
__global__ void k_gram(const u16* __restrict__ QKV, float* __restrict__ Sb)
{
    __shared__ u16 Qt[4][64];
    __shared__ u16 Kt[4][64];
    const int h = blockIdx.x >> 6;
    const int chunk = blockIdx.x & 63;
    const int t = threadIdx.x;
    const int e = t & 63;
    const int dg = t >> 6;
    float acc[16];
    #pragma unroll
    for (int k = 0; k < 16; ++k) acc[k] = 0.f;
    const int rowbase = chunk * 128;
    for (int p = 0; p < 32; ++p) {
        __syncthreads();
        if (t < 64) {
            const int mat = t >> 5, sub = t & 31, r = sub >> 3, seg = sub & 7;
            const int row = rowbase + p * 4 + r;
            const int col = (mat ? 512 : 0) + h * 64 + seg * 8;
            uint4 v = *reinterpret_cast<const uint4*>(QKV + (size_t)row * 1536 + col);
            u16* dst = mat ? &Kt[r][seg * 8] : &Qt[r][seg * 8];
            *reinterpret_cast<uint4*>(dst) = v;
        }
        __syncthreads();
        #pragma unroll
        for (int r = 0; r < 4; ++r) {
            const float q = bf2f(Qt[r][e]);
            short8v kv0 = *reinterpret_cast<const short8v*>(&Kt[r][dg * 16]);
            short8v kv1 = *reinterpret_cast<const short8v*>(&Kt[r][dg * 16 + 8]);
            #pragma unroll
            for (int k = 0; k < 8; ++k) {
                acc[k]     += bf2f((u16)kv0[k]) * q;
                acc[k + 8] += bf2f((u16)kv1[k]) * q;
            }
        }
    }
    #pragma unroll
    for (int k = 0; k < 16; ++k)
        atomicAdd(&Sb[h * 4096 + (dg * 16 + k) * 64 + e], acc[k]);
}

// ---------------------------------------------------------------------------
// attn[h,d,e] = softmax_e( S/(||k_d|| ||q_e||) * rescale[h] )
// ---------------------------------------------------------------------------
__global__ void k_softmax(const float* __restrict__ Sb, const float* __restrict__ colsq,
                          const float* __restrict__ rescale, float* __restrict__ Abuf)
{
    const int h = blockIdx.x;
    const int t = threadIdx.x;   // 64
    const float rsc = rescale[h];
    const float nq = fmaxf(sqrtf(colsq[h * 64 + t]), 1e-12f);
    for (int d = 0; d < 64; ++d) {
        const float nk = fmaxf(sqrtf(colsq[512 + h * 64 + d]), 1e-12f);
        float v = Sb[h * 4096 + d * 64 + t] / (nk * nq) * rsc;
        float m = v;
        #pragma unroll
        for (int off = 32; off > 0; off >>= 1) m = fmaxf(m, __shfl_xor(m, off, 64));
        float p = expf(v - m);
        float s = p;
        #pragma unroll
        for (int off = 32; off > 0; off >>= 1) s += __shfl_xor(s, off, 64);
        Abuf[h * 4096 + d * 64 + t] = p / s;
    }
}

// ---------------------------------------------------------------------------
// BtC[j][c]: c<512 -> fold attn with Wp; c>=512 -> W2. bsum[j] = bp[j]+b2[j].
// ---------------------------------------------------------------------------
__global__ void k_buildbt(const float* __restrict__ Abuf, const float* __restrict__ Wp,
                          const float* __restrict__ W2, const float* __restrict__ bp,
                          const float* __restrict__ b2, u16* __restrict__ BtC,
                          float* __restrict__ bsum)
{
    const int g = blockIdx.x * 256 + threadIdx.x;
    const int j = g >> 10, c = g & 1023;
    if (c < 512) {
        const int h = c >> 6, e = c & 63;
        const float* Ah = Abuf + h * 4096 + e;
        const float* Wph = Wp + (size_t)j * 512 + h * 64;
        float s = 0.f;
        #pragma unroll 8
        for (int d = 0; d < 64; ++d) s += Ah[d * 64] * Wph[d];
        BtC[(size_t)j * 1024 + c] = f2bf(s);
        if (c == 0) bsum[j] = bp[j] + b2[j];
    } else {
        BtC[(size_t)j * 1024 + c] = f2bf(W2[(size_t)j * 512 + (c - 512)]);
    }
}

// ---------------------------------------------------------------------------
extern "C" void kernel_launch(void* const* d_in, const int* in_sizes, int n_in,
                              void* d_out, int out_size, void* d_ws, size_t ws_size,
                              hipStream_t stream)
{
    const float* x_in    = (const float*)d_in[0];
    const float* task_x  = (const float*)d_in[1];
    const float* Ges     = (const float*)d_in[2];
    const float* Wq      = (const float*)d_in[3];
    const float* Wk      = (const float*)d_in[4];
    const float* Wv      = (const float*)d_in[5];
    const float* rescale = (const float*)d_in[6];
    const float* Wp      = (const float*)d_in[7];
    const float* bp      = (const float*)d_in[8];
    const float* W1      = (const float*)d_in[9];
    const float* b1      = (const float*)d_in[10];
    const float* W2      = (const float*)d_in[11];
    const float* b2      = (const float*)d_in[12];
    float* out = (float*)d_out;
    char* ws = (char*)d_ws;

    u16*   XB    = (u16*)  (ws + 0);            //  8192x512  bf16
    u16*   TXT   = (u16*)  (ws + 8388608);      //  512x8192  bf16
    u16*   QKV   = (u16*)  (ws + 16777216);     //  8192x1536 bf16
    u16*   AH    = (u16*)  (ws + 41943040);     //  8192x1024 bf16
    u16*   WqkvB = (u16*)  (ws + 58720256);     //  1536x512  bf16
    u16*   W1B   = (u16*)  (ws + 60293120);     //  512x512   bf16
    u16*   BtC   = (u16*)  (ws + 60817408);     //  512x1024  bf16
    float* colsq = (float*)(ws + 61865984);     //  1024 f32
    float* Sb    = (float*)(ws + 61870080);     //  8x64x64 f32
    float* Abuf  = (float*)(ws + 62001152);     //  8x64x64 f32
    float* bsum  = (float*)(ws + 62132224);     //  512 f32
    (void)in_sizes; (void)n_in; (void)out_size; (void)ws_size;

    hipMemsetAsync(colsq, 0, 4096 + 131072, stream);

    k_convert  <<<2048, 256, 0, stream>>>(x_in, Wq, Wk, Wv, W1, XB, WqkvB, W1B);
    k_transpose<<<dim3(128, 8), 256, 0, stream>>>(task_x, TXT);

    // QKV = x @ [Wq;Wk;Wv]^T   (M=8192, N=1536, K=512)
    gemm_k<0, false><<<dim3(64, 12), 512, 0, stream>>>(
        XB, 512, WqkvB, 512, QKV, 1536, 512, nullptr, nullptr, 0);

    k_colsq  <<<128, 256, 0, stream>>>(QKV, colsq);
    k_gram   <<<512, 256, 0, stream>>>(QKV, Sb);
    k_softmax<<<8, 64, 0, stream>>>(Sb, colsq, rescale, Abuf);
    k_buildbt<<<2048, 256, 0, stream>>>(Abuf, Wp, W2, bp, b2, BtC, bsum);

    // guided = (Ges @ task_x) * V   (M=8192, N=512, K=8192; A fp32)
    gemm_k<1, true><<<dim3(64, 4), 512, 0, stream>>>(
        Ges, 8192, TXT, 8192, AH, 1024, 8192, nullptr, QKV + 1024, 1536);

    // hidden = gelu(V @ W1^T + b1)  (M=8192, N=512, K=512)
    gemm_k<2, false><<<dim3(64, 4), 512, 0, stream>>>(
        QKV + 1024, 1536, W1B, 512, AH + 512, 1024, 512, b1, nullptr, 0);

    // out = [guided|hidden] @ BtC^T + (bp+b2)  (M=8192, N=512, K=1024)
    gemm_k<3, false><<<dim3(64, 4), 512, 0, stream>>>(
        AH, 1024, BtC, 1024, out, 512, 1024, bsum, nullptr, 0);
}